// Round 15
// baseline (118.989 us; speedup 1.0000x reference)
//
#include <hip/hip_runtime.h>
#include <hip/hip_bf16.h>

using bf16 = __hip_bfloat16;
typedef short bf16x8 __attribute__((ext_vector_type(8)));
typedef short s16x4 __attribute__((ext_vector_type(4)));
typedef float f32x4 __attribute__((ext_vector_type(4)));
typedef unsigned int u32x4 __attribute__((ext_vector_type(4)));

#define DD 256
#define MTOT 65536   // B*QH*QW = 16*64*64

static __device__ __forceinline__ short f2bs(float f) {
    bf16 h = __float2bfloat16(f);          // RNE
    return *reinterpret_cast<short*>(&h);
}

// async global->LDS, 16B per lane; LDS dest = wave-uniform base + lane*16
static __device__ __forceinline__ void gll16(const void* g, void* l) {
    __builtin_amdgcn_global_load_lds(
        (const __attribute__((address_space(1))) unsigned int*)g,
        (__attribute__((address_space(3))) unsigned int*)l, 16, 0, 0);
}

// Pre-swizzled BT layout in GLOBAL: element (n = out col, k) at flat
//   n*256 + (((k>>3) ^ (n&7)) << 3 | (k&7))
// 16B-granule XOR closed within each 64-k slice -> LDS staging is a linear
// copy, ds_read at [n][lg ^ (n&7)] bank-optimal (R5/R7: 0 conflicts).
static __device__ __forceinline__ int swz_idx(int n, int k) {
    return n * 256 + ((((k >> 3) ^ (n & 7)) << 3) | (k & 7));
}

// ---------------- K0: merged setup: transpose Wk,Wm + weight folding ----------------
__global__ __launch_bounds__(256) void k_setup(
    const float* __restrict__ Wk, const float* __restrict__ Wm,
    bf16* __restrict__ WkT, bf16* __restrict__ WmT,
    const float* __restrict__ Wb, const float* __restrict__ bb,
    const float* __restrict__ Woff, const float* __restrict__ boff,
    const float* __restrict__ WA, const float* __restrict__ bA,
    bf16* __restrict__ WCt, float* __restrict__ bc)
{
    __shared__ float colw[256];
    __shared__ float red[256];
    int bid = blockIdx.x, t = threadIdx.x;
    if (bid < 512) {
        int idx = bid * 256 + t;
        int which = idx >> 16, e = idx & 65535;
        int i = e >> 8, j = e & 255;               // in[i][j]: i = k, j = n
        const float* src = which == 0 ? Wk : Wm;
        bf16*        dst = which == 0 ? WkT : WmT;
        dst[swz_idx(j, i)] = __float2bfloat16(src[e]);
        return;
    }
    int j = bid - 512;                             // 0..95
    float cw = (j < 64) ? Woff[t * 64 + j] : WA[t * 32 + (j - 64)];
    colw[t] = cw;
    red[t] = bb[t] * cw;
    __syncthreads();
    float v = 0.f;
    const float* wbrow = Wb + (size_t)t * 256;     // WC[k=t][j] = sum_i Wb[t][i]*colw[i]
#pragma unroll 8
    for (int i = 0; i < 256; ++i) v += wbrow[i] * colw[i];
    WCt[swz_idx(j, t)] = __float2bfloat16(v);
    for (int s = 128; s > 0; s >>= 1) {
        __syncthreads();
        if (t < s) red[t] += red[t + s];
    }
    if (t == 0) bc[j] = red[0] + ((j < 64) ? boff[j] : bA[j - 64]);
}

// ---------------- gemm_lds3: f32-A GEMM with T14 reg-staged bf16 A-tile ----------------
// A staged global->reg->cvt->LDS bf16 [64][64k] dbuf (2x8KB), XOR layout
// row*128 + ((g^(row&7))<<4). B: 64-k slices via gll16, single buffer.
// CORRECTNESS (R14 lesson): gll16 writes addrspace(3), loadA reads addrspace(1)
// -> no alias -> compiler may hoist loadA above the gll16s, corrupting the
// counted vmcnt(4). sched_barrier(0) after stageB pins all B-staging OLDER
// than the 4 A-loads, so vmcnt(4) provably drains all of B.
template <int NTW, int NCOLS>
static __device__ __forceinline__ void gemm_lds3(
    const float* __restrict__ Av, const bf16* __restrict__ BTswz,
    bf16* __restrict__ Bs, char* __restrict__ As,   // As: 2*8192 B
    int row0, int tid, f32x4 (&acc)[2][NTW])
{
    const int wave = tid >> 6, lane = tid & 63;
    const int rg = wave >> 1, cg = wave & 1;
    const int rsub = lane & 15, kg = lane >> 4;
    constexpr int SB = NCOLS / 32;
    const int arow_l = lane >> 4;                  // 0..3
    const int kb  = (lane & 15) * 4;               // k base within slice
    const int g_l = (lane & 15) >> 1;              // 16B granule
    const int sub = (lane & 15) & 1;               // 8B half of granule

    f32x4 areg[4];
    auto loadA = [&](int s) {
#pragma unroll
        for (int c = 0; c < 4; ++c) {
            int row = wave * 16 + c * 4 + arow_l;
            areg[c] = *(const f32x4*)(Av + (size_t)(row0 + row) * DD + s * 64 + kb);
        }
    };
    auto writeA = [&](int buf) {
#pragma unroll
        for (int c = 0; c < 4; ++c) {
            int row = wave * 16 + c * 4 + arow_l;
            s16x4 p;
#pragma unroll
            for (int e = 0; e < 4; ++e) p[e] = f2bs(areg[c][e]);
            *(s16x4*)(As + buf * 8192 + row * 128 + ((g_l ^ (row & 7)) << 4) + sub * 8) = p;
        }
    };
    auto stageB = [&](int s) {
#pragma unroll
        for (int i = 0; i < SB; ++i) {
            int cc = wave * SB + i;
            int i16 = cc * 64 + lane;
            int n = i16 >> 3, lg = i16 & 7;
            gll16(BTswz + (size_t)n * 256 + s * 64 + lg * 8, (char*)Bs + (size_t)i16 * 16);
        }
    };

    loadA(0);
    asm volatile("s_waitcnt vmcnt(0)" ::: "memory");
    writeA(0);
    int cur = 0;
#pragma unroll
    for (int s = 0; s < 4; ++s) {
        stageB(s);
        __builtin_amdgcn_sched_barrier(0);   // pin gll16s older than the A-loads
        if (s < 3) {
            loadA(s + 1);                                  // 4 loads stay in flight
            asm volatile("s_waitcnt vmcnt(4)" ::: "memory");   // all B landed
        } else {
            asm volatile("s_waitcnt vmcnt(0)" ::: "memory");
        }
        asm volatile("s_waitcnt lgkmcnt(0)" ::: "memory"); // my A ds_writes committed
        __builtin_amdgcn_s_barrier();
#pragma unroll
        for (int kkl = 0; kkl < 2; ++kkl) {
            bf16x8 afr[2];
#pragma unroll
            for (int st = 0; st < 2; ++st) {
                int row = rg * 32 + st * 16 + rsub;
                int g = kkl * 4 + kg;
                afr[st] = *(const bf16x8*)(As + cur * 8192 + row * 128 + ((g ^ (row & 7)) << 4));
            }
            int lg = kkl * 4 + kg;
#pragma unroll
            for (int nt = 0; nt < NTW; ++nt) {
                int n = cg * (NTW * 16) + nt * 16 + rsub;
                bf16x8 b = *(const bf16x8*)((const char*)Bs + (size_t)n * 128 + ((lg ^ (n & 7)) << 4));
                acc[0][nt] = __builtin_amdgcn_mfma_f32_16x16x32_bf16(afr[0], b, acc[0][nt], 0, 0, 0);
                acc[1][nt] = __builtin_amdgcn_mfma_f32_16x16x32_bf16(afr[1], b, acc[1][nt], 0, 0, 0);
            }
        }
        if (s < 3) {
            asm volatile("s_waitcnt vmcnt(0)" ::: "memory");   // A(s+1) regs arrived
            writeA(cur ^ 1);
        }
        asm volatile("s_waitcnt lgkmcnt(0)" ::: "memory");     // reads+writes drained
        __builtin_amdgcn_s_barrier();
        cur ^= 1;
    }
}

// ---------------- gemm_lds2b (R7) for bf16-A (k_gemm_out) ----------------
template <int NTW, int NCOLS>
static __device__ __forceinline__ void gemm_lds2b(
    const bf16* __restrict__ Av, const bf16* __restrict__ BTswz,
    bf16* __restrict__ Bs, char* __restrict__ As,
    int row0, int tid, f32x4 (&acc)[2][NTW])
{
    const int wave = tid >> 6, lane = tid & 63;
    const int rg = wave >> 1, cg = wave & 1;
    const int rsub = lane & 15, kg = lane >> 4;
    constexpr int SB = NCOLS / 32;
    constexpr int SA = 2;
    constexpr int ABYTES = 8192;

    auto stageB = [&](int s) {
#pragma unroll
        for (int i = 0; i < SB; ++i) {
            int cc = wave * SB + i;
            int i16 = cc * 64 + lane;
            int n = i16 >> 3, lg = i16 & 7;
            gll16(BTswz + (size_t)n * 256 + s * 64 + lg * 8, (char*)Bs + (size_t)i16 * 16);
        }
    };
    auto stageA = [&](int s, int buf) {
#pragma unroll
        for (int i = 0; i < SA; ++i) {
            int cc = wave * 2 + i;
            int row = cc * 8 + (lane >> 3);
            int g = (lane & 7) ^ (row & 7);
            gll16(Av + (size_t)(row0 + row) * DD + s * 64 + g * 8,
                  As + (size_t)buf * ABYTES + cc * 1024 + lane * 16);
        }
    };

    stageA(0, 0);
    int cur = 0;
#pragma unroll
    for (int s = 0; s < 4; ++s) {
        stageB(s);
        __builtin_amdgcn_sched_barrier(0);   // defensive: keep B older than A
        if (s < 3) {
            stageA(s + 1, cur ^ 1);
            asm volatile("s_waitcnt vmcnt(%0)" :: "i"(SA) : "memory");
        } else {
            asm volatile("s_waitcnt vmcnt(0)" ::: "memory");
        }
        __builtin_amdgcn_s_barrier();
#pragma unroll
        for (int kkl = 0; kkl < 2; ++kkl) {
            bf16x8 afr[2];
#pragma unroll
            for (int st = 0; st < 2; ++st) {
                int row = rg * 32 + st * 16 + rsub;
                const char* base = As + cur * ABYTES + row * 128;
                int g = kkl * 4 + kg;
                afr[st] = *(const bf16x8*)(base + ((g ^ (row & 7)) << 4));
            }
            int lg = kkl * 4 + kg;
#pragma unroll
            for (int nt = 0; nt < NTW; ++nt) {
                int n = cg * (NTW * 16) + nt * 16 + rsub;
                bf16x8 b = *(const bf16x8*)((const char*)Bs + (size_t)n * 128 + ((lg ^ (n & 7)) << 4));
                acc[0][nt] = __builtin_amdgcn_mfma_f32_16x16x32_bf16(afr[0], b, acc[0][nt], 0, 0, 0);
                acc[1][nt] = __builtin_amdgcn_mfma_f32_16x16x32_bf16(afr[1], b, acc[1][nt], 0, 0, 0);
            }
        }
        asm volatile("s_waitcnt lgkmcnt(0)" ::: "memory");
        __builtin_amdgcn_s_barrier();
        cur ^= 1;
    }
}

// ---------------- K1: [off | A] = src @ WC + bc ; softmax(A) over K=4 per head ----------------
__global__ __launch_bounds__(256) void k_offA(
    const float* __restrict__ src, const bf16* __restrict__ WCt, const float* __restrict__ bc,
    float* __restrict__ off_ws, float* __restrict__ A_ws)
{
    __shared__ __align__(16) bf16 Bs[96 * 64];    // 12 KB
    __shared__ __align__(16) char As[2 * 8192];   // 16 KB bf16 A dbuf -> 28 KB total
    int tid = threadIdx.x, lane = tid & 63, wave = tid >> 6;
    int row0 = blockIdx.x * 64;
    f32x4 acc[2][3] = {};
    gemm_lds3<3, 96>(src, WCt, Bs, As, row0, tid, acc);
    int col = lane & 15;
    int jbase = (wave & 1) * 48;
    int rb = row0 + (wave >> 1) * 32 + ((lane >> 4) << 2);
#pragma unroll
    for (int mt = 0; mt < 2; ++mt) {
#pragma unroll
        for (int nt = 0; nt < 3; ++nt) {
            int j = jbase + nt * 16 + col;          // 0..95
            if (j < 64) {                           // offsets
                float bias = bc[j];
#pragma unroll
                for (int r = 0; r < 4; ++r) {
                    int m = rb + mt * 16 + r;
                    off_ws[(size_t)m * 64 + j] = acc[mt][nt][r] + bias;
                }
            } else {                                // A logits, ac = j-64 in 0..31
                int ac = j - 64;                    // head = ac>>2, slot = ac&3
                float bias = bc[j];
#pragma unroll
                for (int r = 0; r < 4; ++r) {
                    int m = rb + mt * 16 + r;
                    float v  = acc[mt][nt][r] + bias;
                    float mx = fmaxf(v, __shfl_xor(v, 1));
                    mx       = fmaxf(mx, __shfl_xor(mx, 2));
                    float e  = __expf(v - mx);
                    float su = e + __shfl_xor(e, 1);
                    su      += __shfl_xor(su, 2);
                    A_ws[(size_t)m * 32 + ac] = e / su;
                }
            }
        }
    }
}

// ---------------- K2: kf = keys @ Wk + bk -> bf16 head-split [(b*8+h)*4096 + pix][32] ----
__global__ __launch_bounds__(256) void k_gemm_kf(
    const float* __restrict__ keys, const bf16* __restrict__ WkT,
    const float* __restrict__ bk, bf16* __restrict__ kf)
{
    __shared__ __align__(16) bf16 Bs[256 * 64];   // 32 KB
    __shared__ __align__(16) char As[2 * 8192];   // 16 KB -> 48 KB total (3 blocks/CU)
    int tid = threadIdx.x, lane = tid & 63, wave = tid >> 6;
    int row0 = blockIdx.x * 64;
    f32x4 acc[2][8] = {};
    gemm_lds3<8, 256>(keys, WkT, Bs, As, row0, tid, acc);
    int col = lane & 15;
    int jbase = (wave & 1) * 128;
    int rb = row0 + (wave >> 1) * 32 + ((lane >> 4) << 2);
#pragma unroll
    for (int mt = 0; mt < 2; ++mt)
#pragma unroll
        for (int nt = 0; nt < 8; ++nt) {
            int j = jbase + nt * 16 + col;         // head h=j>>5, channel c=j&31
            float bias = bk[j];
#pragma unroll
            for (int r = 0; r < 4; ++r) {
                int m = rb + mt * 16 + r;          // b = m>>12, pix = m&4095
                size_t dst = (((size_t)(m >> 12) * 8 + (j >> 5)) * 4096 + (m & 4095)) * 32 + (j & 31);
                kf[dst] = __float2bfloat16(acc[mt][nt][r] + bias);
            }
        }
}

// ---------------- K3: bilinear gather (R11 mapping, base-offset for split launch) ----------------
__global__ __launch_bounds__(256) void k_sample(
    const float* __restrict__ ref_point, const float* __restrict__ off_ws,
    const float* __restrict__ A_ws, const bf16* __restrict__ kf,
    bf16* __restrict__ feat, int blk0)
{
    int bid = blockIdx.x + blk0;
    int xcd = bid & 7, within = bid >> 3;
    int b = xcd * 2 + (within >> 9);     // batch 0..15
    int pixblk = within & 511;
    int t  = threadIdx.x;
    int q  = t >> 5;             // 0..7
    int h  = (t >> 2) & 7;       // 0..7
    int cg = t & 3;              // channels cg*8..cg*8+7
    int m  = (b << 12) + pixblk * 8 + q;
    int pix = m & 4095;
    int rbatch = (b * 8 + h) & 15;       // faithful: ref batch = (b*H+h) % B
    const float* rp = ref_point + ((size_t)rbatch * 4096 + pix) * 2;
    float rx = rp[0] * 63.0f;
    float ry = rp[1] * 63.0f;
    const bf16* kfh = kf + ((size_t)(b * 8 + h) * 4096) * 32 + cg * 8;
    f32x4 o0 = *(const f32x4*)(off_ws + (size_t)m * 64 + h * 8);
    f32x4 o1 = *(const f32x4*)(off_ws + (size_t)m * 64 + h * 8 + 4);
    f32x4 av = *(const f32x4*)(A_ws  + (size_t)m * 32 + h * 4);
    float acc[8] = {};
#pragma unroll
    for (int k = 0; k < 4; ++k) {
        float ox = (k < 2) ? o0[2 * k] : o1[2 * k - 4];
        float oy = (k < 2) ? o0[2 * k + 1] : o1[2 * k - 3];
        float a  = av[k];
        float px = (rx + ox) * (64.0f / 63.0f) - 0.5f;   // align_corners=False unnormalize
        float py = (ry + oy) * (64.0f / 63.0f) - 0.5f;
        float x0 = floorf(px), y0 = floorf(py);
        float wx1 = px - x0, wy1 = py - y0;
        int xi = (int)x0, yi = (int)y0;
        float ax0 = (1.f - wx1) * ((xi     >= 0 && xi     < 64) ? 1.f : 0.f);
        float ax1 = wx1         * ((xi + 1 >= 0 && xi + 1 < 64) ? 1.f : 0.f);
        float ay0 = (1.f - wy1) * ((yi     >= 0 && yi     < 64) ? a : 0.f);
        float ay1 = wy1         * ((yi + 1 >= 0 && yi + 1 < 64) ? a : 0.f);
        int xc0 = min(max(xi, 0), 63),      xc1 = min(max(xi + 1, 0), 63);
        int yc0 = min(max(yi, 0), 63) * 64, yc1 = min(max(yi + 1, 0), 63) * 64;
        float w00 = ax0 * ay0, w01 = ax1 * ay0, w10 = ax0 * ay1, w11 = ax1 * ay1;
        bf16x8 v00 = *(const bf16x8*)(kfh + (yc0 + xc0) * 32);
        bf16x8 v01 = *(const bf16x8*)(kfh + (yc0 + xc1) * 32);
        bf16x8 v10 = *(const bf16x8*)(kfh + (yc1 + xc0) * 32);
        bf16x8 v11 = *(const bf16x8*)(kfh + (yc1 + xc1) * 32);
        u32x4 u00 = __builtin_bit_cast(u32x4, v00);
        u32x4 u01 = __builtin_bit_cast(u32x4, v01);
        u32x4 u10 = __builtin_bit_cast(u32x4, v10);
        u32x4 u11 = __builtin_bit_cast(u32x4, v11);
#pragma unroll
        for (int d = 0; d < 4; ++d) {
            acc[2 * d]     += w00 * __uint_as_float(u00[d] << 16)
                            + w01 * __uint_as_float(u01[d] << 16)
                            + w10 * __uint_as_float(u10[d] << 16)
                            + w11 * __uint_as_float(u11[d] << 16);
            acc[2 * d + 1] += w00 * __uint_as_float(u00[d] & 0xffff0000u)
                            + w01 * __uint_as_float(u01[d] & 0xffff0000u)
                            + w10 * __uint_as_float(u10[d] & 0xffff0000u)
                            + w11 * __uint_as_float(u11[d] & 0xffff0000u);
        }
    }
    bf16x8 o;
#pragma unroll
    for (int e = 0; e < 8; ++e) o[e] = f2bs(acc[e]);
    *(bf16x8*)(feat + (size_t)m * DD + h * 32 + cg * 8) = o;
}

// ---------------- K4: out = feat @ Wm + bm -> f32 ----------------
__global__ __launch_bounds__(256) void k_gemm_out(
    const bf16* __restrict__ feat, const bf16* __restrict__ WmT,
    const float* __restrict__ bm, float* __restrict__ out)
{
    __shared__ __align__(16) bf16 Bs[256 * 64];
    __shared__ __align__(16) char As[2 * 8192];
    int tid = threadIdx.x, lane = tid & 63, wave = tid >> 6;
    int row0 = blockIdx.x * 64;
    f32x4 acc[2][8] = {};
    gemm_lds2b<8, 256>(feat, WmT, Bs, As, row0, tid, acc);
    int col = lane & 15;
    int jbase = (wave & 1) * 128;
    int rb = row0 + (wave >> 1) * 32 + ((lane >> 4) << 2);
#pragma unroll
    for (int mt = 0; mt < 2; ++mt)
#pragma unroll
        for (int nt = 0; nt < 8; ++nt) {
            int j = jbase + nt * 16 + col;
            float bias = bm[j];
#pragma unroll
            for (int r = 0; r < 4; ++r)
                out[(size_t)(rb + mt * 16 + r) * DD + j] =
                    acc[mt][nt][r] + bias;
        }
}

extern "C" void kernel_launch(void* const* d_in, const int* in_sizes, int n_in,
                              void* d_out, int out_size, void* d_ws, size_t ws_size,
                              hipStream_t stream)
{
    (void)in_sizes; (void)n_in; (void)out_size; (void)ws_size;
    // setup_inputs order (all float32):
    // 0 query (unused) 1 keys 2 ref_point 3 src_query 4 Wq 5 bq 6 Wb 7 bb
    // 8 Wk 9 bk 10 Woff 11 boff 12 WA 13 bA 14 Wm 15 bm
    const float* keys = (const float*)d_in[1];
    const float* refp = (const float*)d_in[2];
    const float* srcq = (const float*)d_in[3];
    const float* Wb   = (const float*)d_in[6];
    const float* bb   = (const float*)d_in[7];
    const float* Wk   = (const float*)d_in[8];
    const float* bk   = (const float*)d_in[9];
    const float* Woff = (const float*)d_in[10];
    const float* boff = (const float*)d_in[11];
    const float* WA   = (const float*)d_in[12];
    const float* bA   = (const float*)d_in[13];
    const float* Wm   = (const float*)d_in[14];
    const float* bm   = (const float*)d_in[15];

    char* ws = (char*)d_ws;
    bf16*  WkT    = (bf16*)(ws + 0);                    // 128 KiB (swizzled)
    bf16*  WmT    = (bf16*)(ws + 131072);               // 128 KiB (swizzled)
    bf16*  WCt    = (bf16*)(ws + 262144);               // 48 KiB  [96][256] (swizzled, folded)
    float* bc     = (float*)(ws + 311296);              // 384 B
    bf16*  kf_ws  = (bf16*)(ws + 442368 + 33554432ull);             // 32 MiB
    bf16*  feat_ws= (bf16*)(ws + 442368 + 2ull * 33554432ull);      // 32 MiB
    float* off_ws = (float*)(ws + 442368 + 3ull * 33554432ull);     // 16 MiB  [65536][64]
    float* A_ws   = (float*)(ws + 442368 + 3ull * 33554432ull + 16777216ull); // 8 MiB [65536][32]

    float* out = (float*)d_out;

    k_setup    <<<608, 256, 0, stream>>>(Wk, Wm, WkT, WmT, Wb, bb, Woff, boff, WA, bA, WCt, bc);
    k_offA     <<<1024, 256, 0, stream>>>(srcq, WCt, bc, off_ws, A_ws);
    k_gemm_kf  <<<1024, 256, 0, stream>>>(keys, WkT, bk, kf_ws);
    k_sample   <<<4096, 256, 0, stream>>>(refp, off_ws, A_ws, kf_ws, feat_ws, 0);
    k_sample   <<<4096, 256, 0, stream>>>(refp, off_ws, A_ws, kf_ws, feat_ws, 4096);
    k_gemm_out <<<1024, 256, 0, stream>>>(feat_ws, WmT, bm, out);
}

// Round 16
// 114.527 us; speedup vs baseline: 1.0390x; 1.0390x over previous
//
#include <hip/hip_runtime.h>
#include <hip/hip_bf16.h>

using bf16 = __hip_bfloat16;
typedef short bf16x8 __attribute__((ext_vector_type(8)));
typedef short s16x4 __attribute__((ext_vector_type(4)));
typedef float f32x4 __attribute__((ext_vector_type(4)));
typedef unsigned int u32x4 __attribute__((ext_vector_type(4)));

#define DD 256
#define MTOT 65536   // B*QH*QW = 16*64*64

static __device__ __forceinline__ short f2bs(float f) {
    bf16 h = __float2bfloat16(f);          // RNE
    return *reinterpret_cast<short*>(&h);
}

// async global->LDS, 16B per lane; LDS dest = wave-uniform base + lane*16
static __device__ __forceinline__ void gll16(const void* g, void* l) {
    __builtin_amdgcn_global_load_lds(
        (const __attribute__((address_space(1))) unsigned int*)g,
        (__attribute__((address_space(3))) unsigned int*)l, 16, 0, 0);
}

// Pre-swizzled BT layout in GLOBAL: element (n = out col, k) at flat
//   n*256 + (((k>>3) ^ (n&7)) << 3 | (k&7))
// 16B-granule XOR closed within each 64-k slice -> LDS staging is a linear
// copy, ds_read at [n][lg ^ (n&7)] bank-optimal (R5/R7: 0 conflicts).
static __device__ __forceinline__ int swz_idx(int n, int k) {
    return n * 256 + ((((k >> 3) ^ (n & 7)) << 3) | (k & 7));
}

// ---------------- K0: merged setup: transpose Wk,Wm + weight folding ----------------
__global__ __launch_bounds__(256) void k_setup(
    const float* __restrict__ Wk, const float* __restrict__ Wm,
    bf16* __restrict__ WkT, bf16* __restrict__ WmT,
    const float* __restrict__ Wb, const float* __restrict__ bb,
    const float* __restrict__ Woff, const float* __restrict__ boff,
    const float* __restrict__ WA, const float* __restrict__ bA,
    bf16* __restrict__ WCt, float* __restrict__ bc)
{
    __shared__ float colw[256];
    __shared__ float red[256];
    int bid = blockIdx.x, t = threadIdx.x;
    if (bid < 512) {
        int idx = bid * 256 + t;
        int which = idx >> 16, e = idx & 65535;
        int i = e >> 8, j = e & 255;               // in[i][j]: i = k, j = n
        const float* src = which == 0 ? Wk : Wm;
        bf16*        dst = which == 0 ? WkT : WmT;
        dst[swz_idx(j, i)] = __float2bfloat16(src[e]);
        return;
    }
    int j = bid - 512;                             // 0..95
    float cw = (j < 64) ? Woff[t * 64 + j] : WA[t * 32 + (j - 64)];
    colw[t] = cw;
    red[t] = bb[t] * cw;
    __syncthreads();
    float v = 0.f;
    const float* wbrow = Wb + (size_t)t * 256;     // WC[k=t][j] = sum_i Wb[t][i]*colw[i]
#pragma unroll 8
    for (int i = 0; i < 256; ++i) v += wbrow[i] * colw[i];
    WCt[swz_idx(j, t)] = __float2bfloat16(v);
    for (int s = 128; s > 0; s >>= 1) {
        __syncthreads();
        if (t < s) red[t] += red[t + s];
    }
    if (t == 0) bc[j] = red[0] + ((j < 64) ? boff[j] : bA[j - 64]);
}

// ---------------- gemm_lds3: f32-A GEMM, T14 reg-staged bf16 A-tile (R15-verified) ----------------
template <int NTW, int NCOLS>
static __device__ __forceinline__ void gemm_lds3(
    const float* __restrict__ Av, const bf16* __restrict__ BTswz,
    bf16* __restrict__ Bs, char* __restrict__ As,   // As: 2*8192 B
    int row0, int tid, f32x4 (&acc)[2][NTW])
{
    const int wave = tid >> 6, lane = tid & 63;
    const int rg = wave >> 1, cg = wave & 1;
    const int rsub = lane & 15, kg = lane >> 4;
    constexpr int SB = NCOLS / 32;
    const int arow_l = lane >> 4;                  // 0..3
    const int kb  = (lane & 15) * 4;               // k base within slice
    const int g_l = (lane & 15) >> 1;              // 16B granule
    const int sub = (lane & 15) & 1;               // 8B half of granule

    f32x4 areg[4];
    auto loadA = [&](int s) {
#pragma unroll
        for (int c = 0; c < 4; ++c) {
            int row = wave * 16 + c * 4 + arow_l;
            areg[c] = *(const f32x4*)(Av + (size_t)(row0 + row) * DD + s * 64 + kb);
        }
    };
    auto writeA = [&](int buf) {
#pragma unroll
        for (int c = 0; c < 4; ++c) {
            int row = wave * 16 + c * 4 + arow_l;
            s16x4 p;
#pragma unroll
            for (int e = 0; e < 4; ++e) p[e] = f2bs(areg[c][e]);
            *(s16x4*)(As + buf * 8192 + row * 128 + ((g_l ^ (row & 7)) << 4) + sub * 8) = p;
        }
    };
    auto stageB = [&](int s) {
#pragma unroll
        for (int i = 0; i < SB; ++i) {
            int cc = wave * SB + i;
            int i16 = cc * 64 + lane;
            int n = i16 >> 3, lg = i16 & 7;
            gll16(BTswz + (size_t)n * 256 + s * 64 + lg * 8, (char*)Bs + (size_t)i16 * 16);
        }
    };

    loadA(0);
    asm volatile("s_waitcnt vmcnt(0)" ::: "memory");
    writeA(0);
    int cur = 0;
#pragma unroll
    for (int s = 0; s < 4; ++s) {
        stageB(s);
        __builtin_amdgcn_sched_barrier(0);   // pin gll16s older than the A-loads (R14 fix)
        if (s < 3) {
            loadA(s + 1);                                  // 4 loads stay in flight
            asm volatile("s_waitcnt vmcnt(4)" ::: "memory");   // all B landed
        } else {
            asm volatile("s_waitcnt vmcnt(0)" ::: "memory");
        }
        asm volatile("s_waitcnt lgkmcnt(0)" ::: "memory"); // my A ds_writes committed
        __builtin_amdgcn_s_barrier();
#pragma unroll
        for (int kkl = 0; kkl < 2; ++kkl) {
            bf16x8 afr[2];
#pragma unroll
            for (int st = 0; st < 2; ++st) {
                int row = rg * 32 + st * 16 + rsub;
                int g = kkl * 4 + kg;
                afr[st] = *(const bf16x8*)(As + cur * 8192 + row * 128 + ((g ^ (row & 7)) << 4));
            }
            int lg = kkl * 4 + kg;
#pragma unroll
            for (int nt = 0; nt < NTW; ++nt) {
                int n = cg * (NTW * 16) + nt * 16 + rsub;
                bf16x8 b = *(const bf16x8*)((const char*)Bs + (size_t)n * 128 + ((lg ^ (n & 7)) << 4));
                acc[0][nt] = __builtin_amdgcn_mfma_f32_16x16x32_bf16(afr[0], b, acc[0][nt], 0, 0, 0);
                acc[1][nt] = __builtin_amdgcn_mfma_f32_16x16x32_bf16(afr[1], b, acc[1][nt], 0, 0, 0);
            }
        }
        if (s < 3) {
            asm volatile("s_waitcnt vmcnt(0)" ::: "memory");   // A(s+1) regs arrived
            writeA(cur ^ 1);
        }
        asm volatile("s_waitcnt lgkmcnt(0)" ::: "memory");     // reads+writes drained
        __builtin_amdgcn_s_barrier();
        cur ^= 1;
    }
}

// ---------------- gemm_lds2b (R7) for bf16-A (k_gemm_out) ----------------
template <int NTW, int NCOLS>
static __device__ __forceinline__ void gemm_lds2b(
    const bf16* __restrict__ Av, const bf16* __restrict__ BTswz,
    bf16* __restrict__ Bs, char* __restrict__ As,
    int row0, int tid, f32x4 (&acc)[2][NTW])
{
    const int wave = tid >> 6, lane = tid & 63;
    const int rg = wave >> 1, cg = wave & 1;
    const int rsub = lane & 15, kg = lane >> 4;
    constexpr int SB = NCOLS / 32;
    constexpr int SA = 2;
    constexpr int ABYTES = 8192;

    auto stageB = [&](int s) {
#pragma unroll
        for (int i = 0; i < SB; ++i) {
            int cc = wave * SB + i;
            int i16 = cc * 64 + lane;
            int n = i16 >> 3, lg = i16 & 7;
            gll16(BTswz + (size_t)n * 256 + s * 64 + lg * 8, (char*)Bs + (size_t)i16 * 16);
        }
    };
    auto stageA = [&](int s, int buf) {
#pragma unroll
        for (int i = 0; i < SA; ++i) {
            int cc = wave * 2 + i;
            int row = cc * 8 + (lane >> 3);
            int g = (lane & 7) ^ (row & 7);
            gll16(Av + (size_t)(row0 + row) * DD + s * 64 + g * 8,
                  As + (size_t)buf * ABYTES + cc * 1024 + lane * 16);
        }
    };

    stageA(0, 0);
    int cur = 0;
#pragma unroll
    for (int s = 0; s < 4; ++s) {
        stageB(s);
        __builtin_amdgcn_sched_barrier(0);
        if (s < 3) {
            stageA(s + 1, cur ^ 1);
            asm volatile("s_waitcnt vmcnt(%0)" :: "i"(SA) : "memory");
        } else {
            asm volatile("s_waitcnt vmcnt(0)" ::: "memory");
        }
        __builtin_amdgcn_s_barrier();
#pragma unroll
        for (int kkl = 0; kkl < 2; ++kkl) {
            bf16x8 afr[2];
#pragma unroll
            for (int st = 0; st < 2; ++st) {
                int row = rg * 32 + st * 16 + rsub;
                const char* base = As + cur * ABYTES + row * 128;
                int g = kkl * 4 + kg;
                afr[st] = *(const bf16x8*)(base + ((g ^ (row & 7)) << 4));
            }
            int lg = kkl * 4 + kg;
#pragma unroll
            for (int nt = 0; nt < NTW; ++nt) {
                int n = cg * (NTW * 16) + nt * 16 + rsub;
                bf16x8 b = *(const bf16x8*)((const char*)Bs + (size_t)n * 128 + ((lg ^ (n & 7)) << 4));
                acc[0][nt] = __builtin_amdgcn_mfma_f32_16x16x32_bf16(afr[0], b, acc[0][nt], 0, 0, 0);
                acc[1][nt] = __builtin_amdgcn_mfma_f32_16x16x32_bf16(afr[1], b, acc[1][nt], 0, 0, 0);
            }
        }
        asm volatile("s_waitcnt lgkmcnt(0)" ::: "memory");
        __builtin_amdgcn_s_barrier();
        cur ^= 1;
    }
}

// ---------------- body: [off | A] = src @ WC + bc ; softmax(A) ----------------
static __device__ void body_offA(
    int bid, char* smem,
    const float* __restrict__ src, const bf16* __restrict__ WCt, const float* __restrict__ bc,
    float* __restrict__ off_ws, float* __restrict__ A_ws)
{
    bf16* Bs = (bf16*)smem;          // 12 KB
    char* As = smem + 12288;         // 16 KB
    int tid = threadIdx.x, lane = tid & 63, wave = tid >> 6;
    int row0 = bid * 64;
    f32x4 acc[2][3] = {};
    gemm_lds3<3, 96>(src, WCt, Bs, As, row0, tid, acc);
    int col = lane & 15;
    int jbase = (wave & 1) * 48;
    int rb = row0 + (wave >> 1) * 32 + ((lane >> 4) << 2);
#pragma unroll
    for (int mt = 0; mt < 2; ++mt) {
#pragma unroll
        for (int nt = 0; nt < 3; ++nt) {
            int j = jbase + nt * 16 + col;          // 0..95
            if (j < 64) {                           // offsets
                float bias = bc[j];
#pragma unroll
                for (int r = 0; r < 4; ++r) {
                    int m = rb + mt * 16 + r;
                    off_ws[(size_t)m * 64 + j] = acc[mt][nt][r] + bias;
                }
            } else {                                // A logits, ac = j-64 in 0..31
                int ac = j - 64;                    // head = ac>>2, slot = ac&3
                float bias = bc[j];
#pragma unroll
                for (int r = 0; r < 4; ++r) {
                    int m = rb + mt * 16 + r;
                    float v  = acc[mt][nt][r] + bias;
                    float mx = fmaxf(v, __shfl_xor(v, 1));
                    mx       = fmaxf(mx, __shfl_xor(mx, 2));
                    float e  = __expf(v - mx);
                    float su = e + __shfl_xor(e, 1);
                    su      += __shfl_xor(su, 2);
                    A_ws[(size_t)m * 32 + ac] = e / su;
                }
            }
        }
    }
}

// ---------------- body: kf = keys @ Wk + bk ----------------
static __device__ void body_kf(
    int bid, char* smem,
    const float* __restrict__ keys, const bf16* __restrict__ WkT,
    const float* __restrict__ bk, bf16* __restrict__ kf)
{
    bf16* Bs = (bf16*)smem;          // 32 KB
    char* As = smem + 32768;         // 16 KB
    int tid = threadIdx.x, lane = tid & 63, wave = tid >> 6;
    int row0 = bid * 64;
    f32x4 acc[2][8] = {};
    gemm_lds3<8, 256>(keys, WkT, Bs, As, row0, tid, acc);
    int col = lane & 15;
    int jbase = (wave & 1) * 128;
    int rb = row0 + (wave >> 1) * 32 + ((lane >> 4) << 2);
#pragma unroll
    for (int mt = 0; mt < 2; ++mt)
#pragma unroll
        for (int nt = 0; nt < 8; ++nt) {
            int j = jbase + nt * 16 + col;         // head h=j>>5, channel c=j&31
            float bias = bk[j];
#pragma unroll
            for (int r = 0; r < 4; ++r) {
                int m = rb + mt * 16 + r;          // b = m>>12, pix = m&4095
                size_t dst = (((size_t)(m >> 12) * 8 + (j >> 5)) * 4096 + (m & 4095)) * 32 + (j & 31);
                kf[dst] = __float2bfloat16(acc[mt][nt][r] + bias);
            }
        }
}

// ---------------- K1: role-split: even blocks kf, odd blocks offA (independent) ----------------
__global__ __launch_bounds__(256) void k_fusedB(
    const float* __restrict__ src, const bf16* __restrict__ WCt, const float* __restrict__ bc,
    float* __restrict__ off_ws, float* __restrict__ A_ws,
    const float* __restrict__ keys, const bf16* __restrict__ WkT,
    const float* __restrict__ bk, bf16* __restrict__ kf)
{
    __shared__ __align__(16) char smem[49152];   // 48 KB -> 3 blocks/CU both roles
    int bid = blockIdx.x;
    if (bid & 1)
        body_offA(bid >> 1, smem, src, WCt, bc, off_ws, A_ws);
    else
        body_kf(bid >> 1, smem, keys, WkT, bk, kf);
}

// ---------------- K2: bilinear gather (R11 mapping, single launch) ----------------
__global__ __launch_bounds__(256) void k_sample(
    const float* __restrict__ ref_point, const float* __restrict__ off_ws,
    const float* __restrict__ A_ws, const bf16* __restrict__ kf,
    bf16* __restrict__ feat)
{
    int bid = blockIdx.x;
    int xcd = bid & 7, within = bid >> 3;
    int b = xcd * 2 + (within >> 9);     // batch 0..15
    int pixblk = within & 511;
    int t  = threadIdx.x;
    int q  = t >> 5;             // 0..7
    int h  = (t >> 2) & 7;       // 0..7
    int cg = t & 3;              // channels cg*8..cg*8+7
    int m  = (b << 12) + pixblk * 8 + q;
    int pix = m & 4095;
    int rbatch = (b * 8 + h) & 15;       // faithful: ref batch = (b*H+h) % B
    const float* rp = ref_point + ((size_t)rbatch * 4096 + pix) * 2;
    float rx = rp[0] * 63.0f;
    float ry = rp[1] * 63.0f;
    const bf16* kfh = kf + ((size_t)(b * 8 + h) * 4096) * 32 + cg * 8;
    f32x4 o0 = *(const f32x4*)(off_ws + (size_t)m * 64 + h * 8);
    f32x4 o1 = *(const f32x4*)(off_ws + (size_t)m * 64 + h * 8 + 4);
    f32x4 av = *(const f32x4*)(A_ws  + (size_t)m * 32 + h * 4);
    float acc[8] = {};
#pragma unroll
    for (int k = 0; k < 4; ++k) {
        float ox = (k < 2) ? o0[2 * k] : o1[2 * k - 4];
        float oy = (k < 2) ? o0[2 * k + 1] : o1[2 * k - 3];
        float a  = av[k];
        float px = (rx + ox) * (64.0f / 63.0f) - 0.5f;   // align_corners=False unnormalize
        float py = (ry + oy) * (64.0f / 63.0f) - 0.5f;
        float x0 = floorf(px), y0 = floorf(py);
        float wx1 = px - x0, wy1 = py - y0;
        int xi = (int)x0, yi = (int)y0;
        float ax0 = (1.f - wx1) * ((xi     >= 0 && xi     < 64) ? 1.f : 0.f);
        float ax1 = wx1         * ((xi + 1 >= 0 && xi + 1 < 64) ? 1.f : 0.f);
        float ay0 = (1.f - wy1) * ((yi     >= 0 && yi     < 64) ? a : 0.f);
        float ay1 = wy1         * ((yi + 1 >= 0 && yi + 1 < 64) ? a : 0.f);
        int xc0 = min(max(xi, 0), 63),      xc1 = min(max(xi + 1, 0), 63);
        int yc0 = min(max(yi, 0), 63) * 64, yc1 = min(max(yi + 1, 0), 63) * 64;
        float w00 = ax0 * ay0, w01 = ax1 * ay0, w10 = ax0 * ay1, w11 = ax1 * ay1;
        bf16x8 v00 = *(const bf16x8*)(kfh + (yc0 + xc0) * 32);
        bf16x8 v01 = *(const bf16x8*)(kfh + (yc0 + xc1) * 32);
        bf16x8 v10 = *(const bf16x8*)(kfh + (yc1 + xc0) * 32);
        bf16x8 v11 = *(const bf16x8*)(kfh + (yc1 + xc1) * 32);
        u32x4 u00 = __builtin_bit_cast(u32x4, v00);
        u32x4 u01 = __builtin_bit_cast(u32x4, v01);
        u32x4 u10 = __builtin_bit_cast(u32x4, v10);
        u32x4 u11 = __builtin_bit_cast(u32x4, v11);
#pragma unroll
        for (int d = 0; d < 4; ++d) {
            acc[2 * d]     += w00 * __uint_as_float(u00[d] << 16)
                            + w01 * __uint_as_float(u01[d] << 16)
                            + w10 * __uint_as_float(u10[d] << 16)
                            + w11 * __uint_as_float(u11[d] << 16);
            acc[2 * d + 1] += w00 * __uint_as_float(u00[d] & 0xffff0000u)
                            + w01 * __uint_as_float(u01[d] & 0xffff0000u)
                            + w10 * __uint_as_float(u10[d] & 0xffff0000u)
                            + w11 * __uint_as_float(u11[d] & 0xffff0000u);
        }
    }
    bf16x8 o;
#pragma unroll
    for (int e = 0; e < 8; ++e) o[e] = f2bs(acc[e]);
    *(bf16x8*)(feat + (size_t)m * DD + h * 32 + cg * 8) = o;
}

// ---------------- K3: out = feat @ Wm + bm -> f32 ----------------
__global__ __launch_bounds__(256) void k_gemm_out(
    const bf16* __restrict__ feat, const bf16* __restrict__ WmT,
    const float* __restrict__ bm, float* __restrict__ out)
{
    __shared__ __align__(16) bf16 Bs[256 * 64];
    __shared__ __align__(16) char As[2 * 8192];
    int tid = threadIdx.x, lane = tid & 63, wave = tid >> 6;
    int row0 = blockIdx.x * 64;
    f32x4 acc[2][8] = {};
    gemm_lds2b<8, 256>(feat, WmT, Bs, As, row0, tid, acc);
    int col = lane & 15;
    int jbase = (wave & 1) * 128;
    int rb = row0 + (wave >> 1) * 32 + ((lane >> 4) << 2);
#pragma unroll
    for (int mt = 0; mt < 2; ++mt)
#pragma unroll
        for (int nt = 0; nt < 8; ++nt) {
            int j = jbase + nt * 16 + col;
            float bias = bm[j];
#pragma unroll
            for (int r = 0; r < 4; ++r)
                out[(size_t)(rb + mt * 16 + r) * DD + j] =
                    acc[mt][nt][r] + bias;
        }
}

extern "C" void kernel_launch(void* const* d_in, const int* in_sizes, int n_in,
                              void* d_out, int out_size, void* d_ws, size_t ws_size,
                              hipStream_t stream)
{
    (void)in_sizes; (void)n_in; (void)out_size; (void)ws_size;
    // setup_inputs order (all float32):
    // 0 query (unused) 1 keys 2 ref_point 3 src_query 4 Wq 5 bq 6 Wb 7 bb
    // 8 Wk 9 bk 10 Woff 11 boff 12 WA 13 bA 14 Wm 15 bm
    const float* keys = (const float*)d_in[1];
    const float* refp = (const float*)d_in[2];
    const float* srcq = (const float*)d_in[3];
    const float* Wb   = (const float*)d_in[6];
    const float* bb   = (const float*)d_in[7];
    const float* Wk   = (const float*)d_in[8];
    const float* bk   = (const float*)d_in[9];
    const float* Woff = (const float*)d_in[10];
    const float* boff = (const float*)d_in[11];
    const float* WA   = (const float*)d_in[12];
    const float* bA   = (const float*)d_in[13];
    const float* Wm   = (const float*)d_in[14];
    const float* bm   = (const float*)d_in[15];

    char* ws = (char*)d_ws;
    bf16*  WkT    = (bf16*)(ws + 0);                    // 128 KiB (swizzled)
    bf16*  WmT    = (bf16*)(ws + 131072);               // 128 KiB (swizzled)
    bf16*  WCt    = (bf16*)(ws + 262144);               // 48 KiB  [96][256] (swizzled, folded)
    float* bc     = (float*)(ws + 311296);              // 384 B
    bf16*  kf_ws  = (bf16*)(ws + 442368 + 33554432ull);             // 32 MiB
    bf16*  feat_ws= (bf16*)(ws + 442368 + 2ull * 33554432ull);      // 32 MiB
    float* off_ws = (float*)(ws + 442368 + 3ull * 33554432ull);     // 16 MiB  [65536][64]
    float* A_ws   = (float*)(ws + 442368 + 3ull * 33554432ull + 16777216ull); // 8 MiB [65536][32]

    float* out = (float*)d_out;

    k_setup    <<<608, 256, 0, stream>>>(Wk, Wm, WkT, WmT, Wb, bb, Woff, boff, WA, bA, WCt, bc);
    k_fusedB   <<<2048, 256, 0, stream>>>(srcq, WCt, bc, off_ws, A_ws, keys, WkT, bk, kf_ws);
    k_sample   <<<8192, 256, 0, stream>>>(refp, off_ws, A_ws, kf_ws, feat_ws);
    k_gemm_out <<<1024, 256, 0, stream>>>(feat_ws, WmT, bm, out);
}

// Round 17
// 114.316 us; speedup vs baseline: 1.0409x; 1.0018x over previous
//
#include <hip/hip_runtime.h>
#include <hip/hip_bf16.h>

using bf16 = __hip_bfloat16;
typedef short bf16x8 __attribute__((ext_vector_type(8)));
typedef short s16x4 __attribute__((ext_vector_type(4)));
typedef float f32x4 __attribute__((ext_vector_type(4)));
typedef unsigned int u32x4 __attribute__((ext_vector_type(4)));

#define DD 256
#define MTOT 65536   // B*QH*QW = 16*64*64

static __device__ __forceinline__ short f2bs(float f) {
    bf16 h = __float2bfloat16(f);          // RNE
    return *reinterpret_cast<short*>(&h);
}

// async global->LDS, 16B per lane; LDS dest = wave-uniform base + lane*16
static __device__ __forceinline__ void gll16(const void* g, void* l) {
    __builtin_amdgcn_global_load_lds(
        (const __attribute__((address_space(1))) unsigned int*)g,
        (__attribute__((address_space(3))) unsigned int*)l, 16, 0, 0);
}

// Pre-swizzled BT layout in GLOBAL: element (n = out col, k) at flat
//   n*256 + (((k>>3) ^ (n&7)) << 3 | (k&7))
// 16B-granule XOR closed within each 64-k slice -> LDS staging is a linear
// copy, ds_read at [n][lg ^ (n&7)] bank-optimal (R5/R7: 0 conflicts).
static __device__ __forceinline__ int swz_idx(int n, int k) {
    return n * 256 + ((((k >> 3) ^ (n & 7)) << 3) | (k & 7));
}

// ---------------- K0: merged setup: transpose Wk,Wm + weight folding ----------------
__global__ __launch_bounds__(256) void k_setup(
    const float* __restrict__ Wk, const float* __restrict__ Wm,
    bf16* __restrict__ WkT, bf16* __restrict__ WmT,
    const float* __restrict__ Wb, const float* __restrict__ bb,
    const float* __restrict__ Woff, const float* __restrict__ boff,
    const float* __restrict__ WA, const float* __restrict__ bA,
    bf16* __restrict__ WCt, float* __restrict__ bc)
{
    __shared__ float colw[256];
    __shared__ float red[256];
    int bid = blockIdx.x, t = threadIdx.x;
    if (bid < 512) {
        int idx = bid * 256 + t;
        int which = idx >> 16, e = idx & 65535;
        int i = e >> 8, j = e & 255;               // in[i][j]: i = k, j = n
        const float* src = which == 0 ? Wk : Wm;
        bf16*        dst = which == 0 ? WkT : WmT;
        dst[swz_idx(j, i)] = __float2bfloat16(src[e]);
        return;
    }
    int j = bid - 512;                             // 0..95
    float cw = (j < 64) ? Woff[t * 64 + j] : WA[t * 32 + (j - 64)];
    colw[t] = cw;
    red[t] = bb[t] * cw;
    __syncthreads();
    float v = 0.f;
    const float* wbrow = Wb + (size_t)t * 256;     // WC[k=t][j] = sum_i Wb[t][i]*colw[i]
#pragma unroll 8
    for (int i = 0; i < 256; ++i) v += wbrow[i] * colw[i];
    WCt[swz_idx(j, t)] = __float2bfloat16(v);
    for (int s = 128; s > 0; s >>= 1) {
        __syncthreads();
        if (t < s) red[t] += red[t + s];
    }
    if (t == 0) bc[j] = red[0] + ((j < 64) ? boff[j] : bA[j - 64]);
}

// ---------------- gemm_lds4: f32-A GEMM, T3-overlap, BOTH operands double-buffered ----
// A: global->reg->cvt->LDS bf16 [64][64k] dbuf (2x8KB). B: gll16 dbuf (2xBBYTES).
// Slice s: issue {writeA(s+1), stageB(s+1), loadA(s+2)} THEN compute slice s;
// one vmcnt(0)+lgkmcnt(0)+barrier per slice -> staging latency hides under compute.
template <int NTW, int NCOLS>
static __device__ __forceinline__ void gemm_lds4(
    const float* __restrict__ Av, const bf16* __restrict__ BTswz,
    char* __restrict__ Bsc, char* __restrict__ As,   // Bsc: 2*BBYTES, As: 2*8192
    int row0, int tid, f32x4 (&acc)[2][NTW])
{
    const int wave = tid >> 6, lane = tid & 63;
    const int rg = wave >> 1, cg = wave & 1;
    const int rsub = lane & 15, kg = lane >> 4;
    constexpr int SB = NCOLS / 32;
    constexpr int BBYTES = NCOLS * 64 * 2;
    const int arow_l = lane >> 4;                  // 0..3
    const int kb  = (lane & 15) * 4;               // k base within slice
    const int g_l = (lane & 15) >> 1;              // 16B granule
    const int sub = (lane & 15) & 1;               // 8B half of granule

    f32x4 areg[4];
    auto loadA = [&](int s) {
#pragma unroll
        for (int c = 0; c < 4; ++c) {
            int row = wave * 16 + c * 4 + arow_l;
            areg[c] = *(const f32x4*)(Av + (size_t)(row0 + row) * DD + s * 64 + kb);
        }
    };
    auto writeA = [&](int buf) {
#pragma unroll
        for (int c = 0; c < 4; ++c) {
            int row = wave * 16 + c * 4 + arow_l;
            s16x4 p;
#pragma unroll
            for (int e = 0; e < 4; ++e) p[e] = f2bs(areg[c][e]);
            *(s16x4*)(As + buf * 8192 + row * 128 + ((g_l ^ (row & 7)) << 4) + sub * 8) = p;
        }
    };
    auto stageB = [&](int s, int buf) {
#pragma unroll
        for (int i = 0; i < SB; ++i) {
            int cc = wave * SB + i;
            int i16 = cc * 64 + lane;
            int n = i16 >> 3, lg = i16 & 7;
            gll16(BTswz + (size_t)n * 256 + s * 64 + lg * 8,
                  Bsc + buf * BBYTES + (size_t)i16 * 16);
        }
    };

    // prologue: one exposed latency
    loadA(0);
    asm volatile("s_waitcnt vmcnt(0)" ::: "memory");
    writeA(0);
    stageB(0, 0);
    __builtin_amdgcn_sched_barrier(0);
    loadA(1);
    asm volatile("s_waitcnt vmcnt(0)" ::: "memory");     // B(0) in LDS, A(1) in regs
    asm volatile("s_waitcnt lgkmcnt(0)" ::: "memory");   // writeA(0) committed
    __builtin_amdgcn_s_barrier();

    int cur = 0;
#pragma unroll
    for (int s = 0; s < 4; ++s) {
        if (s < 3) {
            writeA(cur ^ 1);          // A(s+1): regs -> LDS (other buffer)
            stageB(s + 1, cur ^ 1);   // B(s+1) in flight across compute
            __builtin_amdgcn_sched_barrier(0);
            if (s < 2) loadA(s + 2);  // A(s+2) -> regs, in flight across compute
            __builtin_amdgcn_sched_barrier(0);
        }
        // compute slice s from buffers [cur]
#pragma unroll
        for (int kkl = 0; kkl < 2; ++kkl) {
            bf16x8 afr[2];
#pragma unroll
            for (int st = 0; st < 2; ++st) {
                int row = rg * 32 + st * 16 + rsub;
                int g = kkl * 4 + kg;
                afr[st] = *(const bf16x8*)(As + cur * 8192 + row * 128 + ((g ^ (row & 7)) << 4));
            }
            int lg = kkl * 4 + kg;
#pragma unroll
            for (int nt = 0; nt < NTW; ++nt) {
                int n = cg * (NTW * 16) + nt * 16 + rsub;
                bf16x8 b = *(const bf16x8*)(Bsc + cur * BBYTES + (size_t)n * 128 + ((lg ^ (n & 7)) << 4));
                acc[0][nt] = __builtin_amdgcn_mfma_f32_16x16x32_bf16(afr[0], b, acc[0][nt], 0, 0, 0);
                acc[1][nt] = __builtin_amdgcn_mfma_f32_16x16x32_bf16(afr[1], b, acc[1][nt], 0, 0, 0);
            }
        }
        asm volatile("s_waitcnt vmcnt(0) lgkmcnt(0)" ::: "memory");  // drain stage+reads+writes
        __builtin_amdgcn_s_barrier();
        cur ^= 1;
    }
}

// ---------------- gemm_lds5: bf16-A GEMM, T3-overlap, both operands gll16 dbuf ----
template <int NTW, int NCOLS>
static __device__ __forceinline__ void gemm_lds5(
    const bf16* __restrict__ Av, const bf16* __restrict__ BTswz,
    char* __restrict__ Bsc, char* __restrict__ As,   // Bsc: 2*BBYTES, As: 2*8192
    int row0, int tid, f32x4 (&acc)[2][NTW])
{
    const int wave = tid >> 6, lane = tid & 63;
    const int rg = wave >> 1, cg = wave & 1;
    const int rsub = lane & 15, kg = lane >> 4;
    constexpr int SB = NCOLS / 32;
    constexpr int BBYTES = NCOLS * 64 * 2;

    auto stageB = [&](int s, int buf) {
#pragma unroll
        for (int i = 0; i < SB; ++i) {
            int cc = wave * SB + i;
            int i16 = cc * 64 + lane;
            int n = i16 >> 3, lg = i16 & 7;
            gll16(BTswz + (size_t)n * 256 + s * 64 + lg * 8,
                  Bsc + buf * BBYTES + (size_t)i16 * 16);
        }
    };
    auto stageA = [&](int s, int buf) {
#pragma unroll
        for (int i = 0; i < 2; ++i) {
            int cc = wave * 2 + i;
            int row = cc * 8 + (lane >> 3);
            int g = (lane & 7) ^ (row & 7);
            gll16(Av + (size_t)(row0 + row) * DD + s * 64 + g * 8,
                  As + (size_t)buf * 8192 + cc * 1024 + lane * 16);
        }
    };

    stageB(0, 0);
    stageA(0, 0);
    asm volatile("s_waitcnt vmcnt(0)" ::: "memory");
    __builtin_amdgcn_s_barrier();

    int cur = 0;
#pragma unroll
    for (int s = 0; s < 4; ++s) {
        if (s < 3) {
            stageB(s + 1, cur ^ 1);
            stageA(s + 1, cur ^ 1);
            __builtin_amdgcn_sched_barrier(0);
        }
#pragma unroll
        for (int kkl = 0; kkl < 2; ++kkl) {
            bf16x8 afr[2];
#pragma unroll
            for (int st = 0; st < 2; ++st) {
                int row = rg * 32 + st * 16 + rsub;
                int g = kkl * 4 + kg;
                afr[st] = *(const bf16x8*)(As + cur * 8192 + row * 128 + ((g ^ (row & 7)) << 4));
            }
            int lg = kkl * 4 + kg;
#pragma unroll
            for (int nt = 0; nt < NTW; ++nt) {
                int n = cg * (NTW * 16) + nt * 16 + rsub;
                bf16x8 b = *(const bf16x8*)(Bsc + cur * BBYTES + (size_t)n * 128 + ((lg ^ (n & 7)) << 4));
                acc[0][nt] = __builtin_amdgcn_mfma_f32_16x16x32_bf16(afr[0], b, acc[0][nt], 0, 0, 0);
                acc[1][nt] = __builtin_amdgcn_mfma_f32_16x16x32_bf16(afr[1], b, acc[1][nt], 0, 0, 0);
            }
        }
        asm volatile("s_waitcnt vmcnt(0) lgkmcnt(0)" ::: "memory");
        __builtin_amdgcn_s_barrier();
        cur ^= 1;
    }
}

// ---------------- K1: [off | A] = src @ WC + bc ; softmax(A) over K=4 per head ----------------
__global__ __launch_bounds__(256) void k_offA(
    const float* __restrict__ src, const bf16* __restrict__ WCt, const float* __restrict__ bc,
    float* __restrict__ off_ws, float* __restrict__ A_ws)
{
    __shared__ __align__(16) char Bsc[2 * 12288];  // 24 KB
    __shared__ __align__(16) char As[2 * 8192];    // 16 KB -> 40 KB total (4 blocks/CU)
    int tid = threadIdx.x, lane = tid & 63, wave = tid >> 6;
    int row0 = blockIdx.x * 64;
    f32x4 acc[2][3] = {};
    gemm_lds4<3, 96>(src, WCt, Bsc, As, row0, tid, acc);
    int col = lane & 15;
    int jbase = (wave & 1) * 48;
    int rb = row0 + (wave >> 1) * 32 + ((lane >> 4) << 2);
#pragma unroll
    for (int mt = 0; mt < 2; ++mt) {
#pragma unroll
        for (int nt = 0; nt < 3; ++nt) {
            int j = jbase + nt * 16 + col;          // 0..95
            if (j < 64) {                           // offsets
                float bias = bc[j];
#pragma unroll
                for (int r = 0; r < 4; ++r) {
                    int m = rb + mt * 16 + r;
                    off_ws[(size_t)m * 64 + j] = acc[mt][nt][r] + bias;
                }
            } else {                                // A logits, ac = j-64 in 0..31
                int ac = j - 64;                    // head = ac>>2, slot = ac&3
                float bias = bc[j];
#pragma unroll
                for (int r = 0; r < 4; ++r) {
                    int m = rb + mt * 16 + r;
                    float v  = acc[mt][nt][r] + bias;
                    float mx = fmaxf(v, __shfl_xor(v, 1));
                    mx       = fmaxf(mx, __shfl_xor(mx, 2));
                    float e  = __expf(v - mx);
                    float su = e + __shfl_xor(e, 1);
                    su      += __shfl_xor(su, 2);
                    A_ws[(size_t)m * 32 + ac] = e / su;
                }
            }
        }
    }
}

// ---------------- K2: kf = keys @ Wk + bk -> bf16 head-split [(b*8+h)*4096 + pix][32] ----
__global__ __launch_bounds__(256) void k_gemm_kf(
    const float* __restrict__ keys, const bf16* __restrict__ WkT,
    const float* __restrict__ bk, bf16* __restrict__ kf)
{
    __shared__ __align__(16) char Bsc[2 * 32768];  // 64 KB
    __shared__ __align__(16) char As[2 * 8192];    // 16 KB -> 80 KB total (2 blocks/CU)
    int tid = threadIdx.x, lane = tid & 63, wave = tid >> 6;
    int row0 = blockIdx.x * 64;
    f32x4 acc[2][8] = {};
    gemm_lds4<8, 256>(keys, WkT, Bsc, As, row0, tid, acc);
    int col = lane & 15;
    int jbase = (wave & 1) * 128;
    int rb = row0 + (wave >> 1) * 32 + ((lane >> 4) << 2);
#pragma unroll
    for (int mt = 0; mt < 2; ++mt)
#pragma unroll
        for (int nt = 0; nt < 8; ++nt) {
            int j = jbase + nt * 16 + col;         // head h=j>>5, channel c=j&31
            float bias = bk[j];
#pragma unroll
            for (int r = 0; r < 4; ++r) {
                int m = rb + mt * 16 + r;          // b = m>>12, pix = m&4095
                size_t dst = (((size_t)(m >> 12) * 8 + (j >> 5)) * 4096 + (m & 4095)) * 32 + (j & 31);
                kf[dst] = __float2bfloat16(acc[mt][nt][r] + bias);
            }
        }
}

// ---------------- K3: bilinear gather (R11 mapping, single launch) ----------------
__global__ __launch_bounds__(256) void k_sample(
    const float* __restrict__ ref_point, const float* __restrict__ off_ws,
    const float* __restrict__ A_ws, const bf16* __restrict__ kf,
    bf16* __restrict__ feat)
{
    int bid = blockIdx.x;
    int xcd = bid & 7, within = bid >> 3;
    int b = xcd * 2 + (within >> 9);     // batch 0..15
    int pixblk = within & 511;
    int t  = threadIdx.x;
    int q  = t >> 5;             // 0..7
    int h  = (t >> 2) & 7;       // 0..7
    int cg = t & 3;              // channels cg*8..cg*8+7
    int m  = (b << 12) + pixblk * 8 + q;
    int pix = m & 4095;
    int rbatch = (b * 8 + h) & 15;       // faithful: ref batch = (b*H+h) % B
    const float* rp = ref_point + ((size_t)rbatch * 4096 + pix) * 2;
    float rx = rp[0] * 63.0f;
    float ry = rp[1] * 63.0f;
    const bf16* kfh = kf + ((size_t)(b * 8 + h) * 4096) * 32 + cg * 8;
    f32x4 o0 = *(const f32x4*)(off_ws + (size_t)m * 64 + h * 8);
    f32x4 o1 = *(const f32x4*)(off_ws + (size_t)m * 64 + h * 8 + 4);
    f32x4 av = *(const f32x4*)(A_ws  + (size_t)m * 32 + h * 4);
    float acc[8] = {};
#pragma unroll
    for (int k = 0; k < 4; ++k) {
        float ox = (k < 2) ? o0[2 * k] : o1[2 * k - 4];
        float oy = (k < 2) ? o0[2 * k + 1] : o1[2 * k - 3];
        float a  = av[k];
        float px = (rx + ox) * (64.0f / 63.0f) - 0.5f;   // align_corners=False unnormalize
        float py = (ry + oy) * (64.0f / 63.0f) - 0.5f;
        float x0 = floorf(px), y0 = floorf(py);
        float wx1 = px - x0, wy1 = py - y0;
        int xi = (int)x0, yi = (int)y0;
        float ax0 = (1.f - wx1) * ((xi     >= 0 && xi     < 64) ? 1.f : 0.f);
        float ax1 = wx1         * ((xi + 1 >= 0 && xi + 1 < 64) ? 1.f : 0.f);
        float ay0 = (1.f - wy1) * ((yi     >= 0 && yi     < 64) ? a : 0.f);
        float ay1 = wy1         * ((yi + 1 >= 0 && yi + 1 < 64) ? a : 0.f);
        int xc0 = min(max(xi, 0), 63),      xc1 = min(max(xi + 1, 0), 63);
        int yc0 = min(max(yi, 0), 63) * 64, yc1 = min(max(yi + 1, 0), 63) * 64;
        float w00 = ax0 * ay0, w01 = ax1 * ay0, w10 = ax0 * ay1, w11 = ax1 * ay1;
        bf16x8 v00 = *(const bf16x8*)(kfh + (yc0 + xc0) * 32);
        bf16x8 v01 = *(const bf16x8*)(kfh + (yc0 + xc1) * 32);
        bf16x8 v10 = *(const bf16x8*)(kfh + (yc1 + xc0) * 32);
        bf16x8 v11 = *(const bf16x8*)(kfh + (yc1 + xc1) * 32);
        u32x4 u00 = __builtin_bit_cast(u32x4, v00);
        u32x4 u01 = __builtin_bit_cast(u32x4, v01);
        u32x4 u10 = __builtin_bit_cast(u32x4, v10);
        u32x4 u11 = __builtin_bit_cast(u32x4, v11);
#pragma unroll
        for (int d = 0; d < 4; ++d) {
            acc[2 * d]     += w00 * __uint_as_float(u00[d] << 16)
                            + w01 * __uint_as_float(u01[d] << 16)
                            + w10 * __uint_as_float(u10[d] << 16)
                            + w11 * __uint_as_float(u11[d] << 16);
            acc[2 * d + 1] += w00 * __uint_as_float(u00[d] & 0xffff0000u)
                            + w01 * __uint_as_float(u01[d] & 0xffff0000u)
                            + w10 * __uint_as_float(u10[d] & 0xffff0000u)
                            + w11 * __uint_as_float(u11[d] & 0xffff0000u);
        }
    }
    bf16x8 o;
#pragma unroll
    for (int e = 0; e < 8; ++e) o[e] = f2bs(acc[e]);
    *(bf16x8*)(feat + (size_t)m * DD + h * 32 + cg * 8) = o;
}

// ---------------- K4: out = feat @ Wm + bm -> f32 ----------------
__global__ __launch_bounds__(256) void k_gemm_out(
    const bf16* __restrict__ feat, const bf16* __restrict__ WmT,
    const float* __restrict__ bm, float* __restrict__ out)
{
    __shared__ __align__(16) char Bsc[2 * 32768];  // 64 KB
    __shared__ __align__(16) char As[2 * 8192];    // 16 KB -> 80 KB total
    int tid = threadIdx.x, lane = tid & 63, wave = tid >> 6;
    int row0 = blockIdx.x * 64;
    f32x4 acc[2][8] = {};
    gemm_lds5<8, 256>(feat, WmT, Bsc, As, row0, tid, acc);
    int col = lane & 15;
    int jbase = (wave & 1) * 128;
    int rb = row0 + (wave >> 1) * 32 + ((lane >> 4) << 2);
#pragma unroll
    for (int mt = 0; mt < 2; ++mt)
#pragma unroll
        for (int nt = 0; nt < 8; ++nt) {
            int j = jbase + nt * 16 + col;
            float bias = bm[j];
#pragma unroll
            for (int r = 0; r < 4; ++r)
                out[(size_t)(rb + mt * 16 + r) * DD + j] =
                    acc[mt][nt][r] + bias;
        }
}

extern "C" void kernel_launch(void* const* d_in, const int* in_sizes, int n_in,
                              void* d_out, int out_size, void* d_ws, size_t ws_size,
                              hipStream_t stream)
{
    (void)in_sizes; (void)n_in; (void)out_size; (void)ws_size;
    // setup_inputs order (all float32):
    // 0 query (unused) 1 keys 2 ref_point 3 src_query 4 Wq 5 bq 6 Wb 7 bb
    // 8 Wk 9 bk 10 Woff 11 boff 12 WA 13 bA 14 Wm 15 bm
    const float* keys = (const float*)d_in[1];
    const float* refp = (const float*)d_in[2];
    const float* srcq = (const float*)d_in[3];
    const float* Wb   = (const float*)d_in[6];
    const float* bb   = (const float*)d_in[7];
    const float* Wk   = (const float*)d_in[8];
    const float* bk   = (const float*)d_in[9];
    const float* Woff = (const float*)d_in[10];
    const float* boff = (const float*)d_in[11];
    const float* WA   = (const float*)d_in[12];
    const float* bA   = (const float*)d_in[13];
    const float* Wm   = (const float*)d_in[14];
    const float* bm   = (const float*)d_in[15];

    char* ws = (char*)d_ws;
    bf16*  WkT    = (bf16*)(ws + 0);                    // 128 KiB (swizzled)
    bf16*  WmT    = (bf16*)(ws + 131072);               // 128 KiB (swizzled)
    bf16*  WCt    = (bf16*)(ws + 262144);               // 48 KiB  [96][256] (swizzled, folded)
    float* bc     = (float*)(ws + 311296);              // 384 B
    bf16*  kf_ws  = (bf16*)(ws + 442368 + 33554432ull);             // 32 MiB
    bf16*  feat_ws= (bf16*)(ws + 442368 + 2ull * 33554432ull);      // 32 MiB
    float* off_ws = (float*)(ws + 442368 + 3ull * 33554432ull);     // 16 MiB  [65536][64]
    float* A_ws   = (float*)(ws + 442368 + 3ull * 33554432ull + 16777216ull); // 8 MiB [65536][32]

    float* out = (float*)d_out;

    k_setup    <<<608, 256, 0, stream>>>(Wk, Wm, WkT, WmT, Wb, bb, Woff, boff, WA, bA, WCt, bc);
    k_offA     <<<1024, 256, 0, stream>>>(srcq, WCt, bc, off_ws, A_ws);
    k_gemm_kf  <<<1024, 256, 0, stream>>>(keys, WkT, bk, kf_ws);
    k_sample   <<<8192, 256, 0, stream>>>(refp, off_ws, A_ws, kf_ws, feat_ws);
    k_gemm_out <<<1024, 256, 0, stream>>>(feat_ws, WmT, bm, out);
}